// Round 1
// baseline (215.732 us; speedup 1.0000x reference)
//
#include <hip/hip_runtime.h>
#include <hip/hip_bf16.h>
#include <cstdint>
#include <cstddef>

typedef _Float16 half8 __attribute__((ext_vector_type(8)));
typedef float floatx16 __attribute__((ext_vector_type(16)));

#define DGRID 128
#define D3 (DGRID * DGRID * DGRID)

// lookup[lin(voxel)] = point index (pre-memset to -1 via 0xFF)
__global__ void scatter_lookup(const int* __restrict__ coords, int* __restrict__ lookup, int M) {
    int m = blockIdx.x * 256 + threadIdx.x;
    if (m >= M) return;
    int x = coords[3 * m], y = coords[3 * m + 1], z = coords[3 * m + 2];
    lookup[(x * DGRID + y) * DGRID + z] = m;
}

// nbr[k*M + m] = point index of neighbor at offset k (or -1). Shared by both layers.
__global__ void build_nbr(const int* __restrict__ coords, const int* __restrict__ lookup,
                          int* __restrict__ nbr, int M) {
    int m = blockIdx.x * 256 + threadIdx.x;
    if (m >= M) return;
    int x = coords[3 * m], y = coords[3 * m + 1], z = coords[3 * m + 2];
#pragma unroll
    for (int k = 0; k < 27; ++k) {
        int nx = x + k / 9 - 1, ny = y + (k / 3) % 3 - 1, nz = z + k % 3 - 1;
        int nidx = -1;
        if (((unsigned)nx < DGRID) && ((unsigned)ny < DGRID) && ((unsigned)nz < DGRID))
            nidx = lookup[(nx * DGRID + ny) * DGRID + nz];
        nbr[k * M + m] = nidx;
    }
}

// Wh[(L*27 + k)*4096 + n*64 + c] = (fp16) W_L[k][c][n]   (transposed: n-major, c-contig)
__global__ void convert_weights(const float* __restrict__ W1, const float* __restrict__ W2,
                                _Float16* __restrict__ Wh) {
    int idx = blockIdx.x * 256 + threadIdx.x;
    if (idx >= 2 * 27 * 4096) return;
    const float* W = (idx < 27 * 4096) ? W1 : W2;
    int r = idx % (27 * 4096);
    int k = r >> 12;
    int n = (r >> 6) & 63;
    int c = r & 63;
    Wh[idx] = (_Float16)W[k * 4096 + c * 64 + n];
}

// One block = 64 output points x 64 channels. Dense k-loop over 27 offsets:
// gather valid neighbor rows (zeros if absent) into LDS A, W_k^T into LDS B,
// accumulate with mfma_f32_32x32x16_f16 (4 waves, each a 32x32 C tile).
template <typename SrcT, bool OUT_F16>
__global__ __launch_bounds__(256) void conv64(const SrcT* __restrict__ x,
                                              const _Float16* __restrict__ Wh,
                                              const float* __restrict__ bias,
                                              const int* __restrict__ nbr,
                                              void* __restrict__ outp, int M) {
    constexpr int STR = 88;  // halves; 176 B = 11*16 B: aligned b128, conflict-free octets
    __shared__ __align__(16) _Float16 As[64 * STR];
    __shared__ __align__(16) _Float16 Bs[64 * STR];
    const int t = threadIdx.x;
    const int lane = t & 63;
    const int wave = t >> 6;
    const int m0 = blockIdx.x * 64;
    const int r0 = (wave >> 1) * 32;  // C-tile row base for this wave
    const int c0 = (wave & 1) * 32;   // C-tile col base
    const int lrow = lane & 31;
    const int lhalf = lane >> 5;

    floatx16 acc;
#pragma unroll
    for (int i = 0; i < 16; ++i) acc[i] = 0.0f;

    const int srow = t >> 3;  // staging row 0..31 (+32 on 2nd pass)
    const int c4 = t & 7;     // 16B chunk within row

    for (int k = 0; k < 27; ++k) {
        __syncthreads();  // previous iter's LDS reads done
        // --- stage W_k^T: 64 rows(n) x 64(c) fp16 = 512 x 16B chunks, 2 per thread
        const uint4* wsrc = (const uint4*)(Wh + k * 4096);
#pragma unroll
        for (int i = 0; i < 2; ++i) {
            int id = t + i * 256;
            int n = id >> 3, cc = id & 7;
            *(uint4*)&Bs[n * STR + cc * 8] = wsrc[id];
        }
        // --- stage gathered A: 64 rows x 64 ch fp16; zeros for invalid/tail rows
#pragma unroll
        for (int i = 0; i < 2; ++i) {
            int r = srow + i * 32;
            int gm = m0 + r;
            int nidx = (gm < M) ? nbr[k * M + gm] : -1;
            half8 v;
            if (nidx >= 0) {
                if constexpr (sizeof(SrcT) == 4) {
                    const float4* src = (const float4*)(x + (size_t)nidx * 64) + c4 * 2;
                    float4 f0 = src[0], f1 = src[1];
                    v[0] = (_Float16)f0.x; v[1] = (_Float16)f0.y;
                    v[2] = (_Float16)f0.z; v[3] = (_Float16)f0.w;
                    v[4] = (_Float16)f1.x; v[5] = (_Float16)f1.y;
                    v[6] = (_Float16)f1.z; v[7] = (_Float16)f1.w;
                } else {
                    v = *(const half8*)((const _Float16*)x + (size_t)nidx * 64 + c4 * 8);
                }
            } else {
#pragma unroll
                for (int j = 0; j < 8; ++j) v[j] = (_Float16)0.f;
            }
            *(half8*)&As[r * STR + c4 * 8] = v;
        }
        __syncthreads();
        // --- MFMA: C[32x32] += A[32xK=64] * B[K=64x32], 4 K-steps of 16
#pragma unroll
        for (int kk = 0; kk < 4; ++kk) {
            half8 a = *(half8*)&As[(r0 + lrow) * STR + kk * 16 + lhalf * 8];
            half8 b = *(half8*)&Bs[(c0 + lrow) * STR + kk * 16 + lhalf * 8];
            acc = __builtin_amdgcn_mfma_f32_32x32x16_f16(a, b, acc, 0, 0, 0);
        }
    }

    // epilogue: bias + relu; C/D layout: col=lane&31, row=(reg&3)+8*(reg>>2)+4*(lane>>5)
    float bval = bias[c0 + lrow];
#pragma unroll
    for (int reg = 0; reg < 16; ++reg) {
        int row = (reg & 3) + 8 * (reg >> 2) + 4 * lhalf;
        int gm = m0 + r0 + row;
        if (gm < M) {
            float v = acc[reg] + bval;
            v = v > 0.f ? v : 0.f;
            size_t off = (size_t)gm * 64 + c0 + lrow;
            if constexpr (OUT_F16)
                ((_Float16*)outp)[off] = (_Float16)v;
            else
                ((float*)outp)[off] = v;
        }
    }
}

extern "C" void kernel_launch(void* const* d_in, const int* in_sizes, int n_in,
                              void* d_out, int out_size, void* d_ws, size_t ws_size,
                              hipStream_t stream) {
    const float* feats = (const float*)d_in[0];
    const float* W1 = (const float*)d_in[1];
    const float* b1 = (const float*)d_in[2];
    const float* W2 = (const float*)d_in[3];
    const float* b2 = (const float*)d_in[4];
    const int* coords = (const int*)d_in[5];
    const int M = in_sizes[0] / 64;

    // workspace layout (all 16B-aligned given M=100000):
    int* lookup = (int*)d_ws;                          // D3 ints       = 8 MB
    int* nbr = lookup + (size_t)D3;                    // 27*M ints     = 10.8 MB
    _Float16* h = (_Float16*)(nbr + (size_t)27 * M);   // M*64 halves   = 12.8 MB
    _Float16* Wh = h + (size_t)M * 64;                 // 2*27*4096 halves = 432 KB
    size_t need = (size_t)D3 * 4 + (size_t)27 * M * 4 + (size_t)M * 64 * 2 +
                  (size_t)2 * 27 * 4096 * 2;
    if (ws_size < need) return;  // avoid OOB scribbling; shows as clean mismatch

    hipMemsetAsync(lookup, 0xFF, (size_t)D3 * 4, stream);  // -1 everywhere
    int mb = (M + 255) / 256;
    scatter_lookup<<<mb, 256, 0, stream>>>(coords, lookup, M);
    convert_weights<<<(2 * 27 * 4096 + 255) / 256, 256, 0, stream>>>(W1, W2, Wh);
    build_nbr<<<mb, 256, 0, stream>>>(coords, lookup, nbr, M);

    int cb = (M + 63) / 64;
    conv64<float, true><<<cb, 256, 0, stream>>>(feats, Wh, b1, nbr, (void*)h, M);
    conv64<_Float16, false><<<cb, 256, 0, stream>>>(h, Wh + 27 * 4096, b2, nbr, d_out, M);
}

// Round 2
// 197.645 us; speedup vs baseline: 1.0915x; 1.0915x over previous
//
#include <hip/hip_runtime.h>
#include <hip/hip_bf16.h>
#include <cstdint>
#include <cstddef>

typedef _Float16 half8 __attribute__((ext_vector_type(8)));
typedef float floatx16 __attribute__((ext_vector_type(16)));

#define DGRID 128
#define D3 (DGRID * DGRID * DGRID)

// lookup[lin(voxel)] = point index (pre-memset to -1 via 0xFF)
__global__ void scatter_lookup(const int* __restrict__ coords, int* __restrict__ lookup, int M) {
    int m = blockIdx.x * 256 + threadIdx.x;
    if (m >= M) return;
    int x = coords[3 * m], y = coords[3 * m + 1], z = coords[3 * m + 2];
    lookup[(x * DGRID + y) * DGRID + z] = m;
}

// nbr[k*M + m] = point index of neighbor at offset k (or -1). Shared by both layers.
__global__ void build_nbr(const int* __restrict__ coords, const int* __restrict__ lookup,
                          int* __restrict__ nbr, int M) {
    int m = blockIdx.x * 256 + threadIdx.x;
    if (m >= M) return;
    int x = coords[3 * m], y = coords[3 * m + 1], z = coords[3 * m + 2];
#pragma unroll
    for (int k = 0; k < 27; ++k) {
        int nx = x + k / 9 - 1, ny = y + (k / 3) % 3 - 1, nz = z + k % 3 - 1;
        int nidx = -1;
        if (((unsigned)nx < DGRID) && ((unsigned)ny < DGRID) && ((unsigned)nz < DGRID))
            nidx = lookup[(nx * DGRID + ny) * DGRID + nz];
        nbr[k * M + m] = nidx;
    }
}

// Whf in MFMA B-fragment order: for layer L, offset k, frag f=ct*4+kk, lane l, j in 0..7:
//   Whf[((L*27+k)*8+f)*512 + l*8 + j] = (fp16) W_L[k][ c=kk*16+(l>>5)*8+j ][ n=ct*32+(l&31) ]
// so a wave loads W_k's full B operand as 8 coalesced 1KB loads (b-frag = half8 per lane).
__global__ void convert_weights(const float* __restrict__ W1, const float* __restrict__ W2,
                                _Float16* __restrict__ Whf) {
    int idx = blockIdx.x * 256 + threadIdx.x;
    if (idx >= 2 * 27 * 4096) return;
    int j = idx & 7;
    int l = (idx >> 3) & 63;
    int f = (idx >> 9) & 7;
    int kL = idx >> 12;  // 0..53
    int k = kL % 27, L = kL / 27;
    int kk = f & 3, ct = f >> 2;
    int c = kk * 16 + (l >> 5) * 8 + j;
    int n = ct * 32 + (l & 31);
    const float* W = L ? W2 : W1;
    Whf[idx] = (_Float16)W[k * 4096 + c * 64 + n];
}

// One wave (= one 64-thread block) computes 64 points x 64 channels.
// No LDS, no barriers: B fragments register-resident from fragment-ordered Whf
// (L2-hot), A gathered direct global->register with per-lane predication.
// Software pipeline: A/B prefetch depth 1, nbr depth 2; k fully unrolled.
template <typename SrcT, bool OUT_F16>
__global__ __launch_bounds__(64) void spconv(const SrcT* __restrict__ x,
                                             const _Float16* __restrict__ Whf,
                                             const float* __restrict__ bias,
                                             const int* __restrict__ nbr,
                                             void* __restrict__ outp, int M) {
    const int lane = threadIdx.x;
    const int lrow = lane & 31;
    const int lhalf = lane >> 5;
    const int mw = blockIdx.x * 64;
    const int gm0 = mw + lrow;
    const int gm1 = mw + 32 + lrow;
    const bool in0 = gm0 < M, in1 = gm1 < M;

    floatx16 acc[4];  // [rt*2+ct], 32x32 C tiles
#pragma unroll
    for (int i = 0; i < 4; ++i)
#pragma unroll
        for (int j = 0; j < 16; ++j) acc[i][j] = 0.0f;

    const half8* wb = (const half8*)Whf + lane;  // + (k*8+f)*64

    half8 A[8], B[8];  // current k fragments: A[rt*4+kk], B[ct*4+kk]

    // gather A fragments for one k given the two row-tile neighbor indices
    auto loadA = [&](half8* dst, int n0, int n1) {
#pragma unroll
        for (int rt = 0; rt < 2; ++rt) {
            int n = rt ? n1 : n0;
#pragma unroll
            for (int kk = 0; kk < 4; ++kk) {
                half8 z;
#pragma unroll
                for (int j = 0; j < 8; ++j) z[j] = (_Float16)0.f;
                dst[rt * 4 + kk] = z;
            }
            if (n >= 0) {
                if constexpr (sizeof(SrcT) == 4) {
                    const float4* p =
                        (const float4*)((const float*)x + (size_t)n * 64 + lhalf * 8);
#pragma unroll
                    for (int kk = 0; kk < 4; ++kk) {
                        float4 f0 = p[kk * 4], f1 = p[kk * 4 + 1];
                        half8 v;
                        v[0] = (_Float16)f0.x; v[1] = (_Float16)f0.y;
                        v[2] = (_Float16)f0.z; v[3] = (_Float16)f0.w;
                        v[4] = (_Float16)f1.x; v[5] = (_Float16)f1.y;
                        v[6] = (_Float16)f1.z; v[7] = (_Float16)f1.w;
                        dst[rt * 4 + kk] = v;
                    }
                } else {
                    const half8* p =
                        (const half8*)((const _Float16*)x + (size_t)n * 64 + lhalf * 8);
#pragma unroll
                    for (int kk = 0; kk < 4; ++kk) dst[rt * 4 + kk] = p[kk * 2];
                }
            }
        }
    };

    // prologue: nbr(0), B(0), A(0), nbr(1)
    int n0 = -1, n1 = -1;
    if (in0) n0 = nbr[gm0];
    if (in1) n1 = nbr[gm1];
    int n0n = -1, n1n = -1;
    if (in0) n0n = nbr[M + gm0];
    if (in1) n1n = nbr[M + gm1];
#pragma unroll
    for (int f = 0; f < 8; ++f) B[f] = wb[f * 64];
    loadA(A, n0, n1);

#pragma unroll
    for (int k = 0; k < 27; ++k) {
        const int kn = (k + 1 < 27) ? k + 1 : 26;   // next-iter A/B (clamped, redundant at tail)
        const int kn2 = (k + 2 < 27) ? k + 2 : 26;  // nbr depth-2
        half8 Bn[8], An[8];
#pragma unroll
        for (int f = 0; f < 8; ++f) Bn[f] = wb[(kn * 8 + f) * 64];
        const int n0f = n0n, n1f = n1n;  // nidx(k+1), loaded last iter
        n0n = -1; n1n = -1;
        if (in0) n0n = nbr[(size_t)kn2 * M + gm0];
        if (in1) n1n = nbr[(size_t)kn2 * M + gm1];
        loadA(An, n0f, n1f);
        // compute k with A,B
#pragma unroll
        for (int rt = 0; rt < 2; ++rt)
#pragma unroll
            for (int ct = 0; ct < 2; ++ct)
#pragma unroll
                for (int kk = 0; kk < 4; ++kk)
                    acc[rt * 2 + ct] = __builtin_amdgcn_mfma_f32_32x32x16_f16(
                        A[rt * 4 + kk], B[ct * 4 + kk], acc[rt * 2 + ct], 0, 0, 0);
#pragma unroll
        for (int f = 0; f < 8; ++f) { A[f] = An[f]; B[f] = Bn[f]; }
    }

    // epilogue: bias + relu; C/D: col=lane&31, row=(reg&3)+8*(reg>>2)+4*lhalf
    const float bv0 = bias[lrow];
    const float bv1 = bias[32 + lrow];
#pragma unroll
    for (int rt = 0; rt < 2; ++rt)
#pragma unroll
        for (int ct = 0; ct < 2; ++ct) {
            const float bb = ct ? bv1 : bv0;
#pragma unroll
            for (int reg = 0; reg < 16; ++reg) {
                int row = (reg & 3) + 8 * (reg >> 2) + 4 * lhalf;
                int gm = mw + rt * 32 + row;
                if (gm < M) {
                    float v = acc[rt * 2 + ct][reg] + bb;
                    v = v > 0.f ? v : 0.f;
                    size_t off = (size_t)gm * 64 + ct * 32 + lrow;
                    if constexpr (OUT_F16)
                        ((_Float16*)outp)[off] = (_Float16)v;
                    else
                        ((float*)outp)[off] = v;
                }
            }
        }
}

extern "C" void kernel_launch(void* const* d_in, const int* in_sizes, int n_in,
                              void* d_out, int out_size, void* d_ws, size_t ws_size,
                              hipStream_t stream) {
    const float* feats = (const float*)d_in[0];
    const float* W1 = (const float*)d_in[1];
    const float* b1 = (const float*)d_in[2];
    const float* W2 = (const float*)d_in[3];
    const float* b2 = (const float*)d_in[4];
    const int* coords = (const int*)d_in[5];
    const int M = in_sizes[0] / 64;

    // workspace layout (same footprint as round 1, which fit):
    int* lookup = (int*)d_ws;                          // D3 ints       = 8.4 MB
    int* nbr = lookup + (size_t)D3;                    // 27*M ints     = 10.8 MB
    _Float16* h = (_Float16*)(nbr + (size_t)27 * M);   // M*64 halves   = 12.8 MB
    _Float16* Whf = h + (size_t)M * 64;                // 2*27*4096 halves
    size_t need = (size_t)D3 * 4 + (size_t)27 * M * 4 + (size_t)M * 64 * 2 +
                  (size_t)2 * 27 * 4096 * 2;
    if (ws_size < need) return;

    hipMemsetAsync(lookup, 0xFF, (size_t)D3 * 4, stream);  // -1 everywhere
    int mb = (M + 255) / 256;
    scatter_lookup<<<mb, 256, 0, stream>>>(coords, lookup, M);
    convert_weights<<<(2 * 27 * 4096 + 255) / 256, 256, 0, stream>>>(W1, W2, Whf);
    build_nbr<<<mb, 256, 0, stream>>>(coords, lookup, nbr, M);

    int cb = (M + 63) / 64;
    spconv<float, true><<<cb, 64, 0, stream>>>(feats, Whf, b1, nbr, (void*)h, M);
    spconv<_Float16, false><<<cb, 64, 0, stream>>>(h, Whf + (size_t)27 * 4096, b2, nbr,
                                                   d_out, M);
}